// Round 1
// baseline (833.700 us; speedup 1.0000x reference)
//
#include <hip/hip_runtime.h>
#include <hip/hip_bf16.h>

// Problem constants (from reference)
#define NS   16384   // samples
#define NC   64      // components (M)
#define DIN  128     // K
#define DOUT 128     // Q
#define NSP  8       // species

typedef __attribute__((ext_vector_type(8))) short short8;   // 8 bf16 = 4 VGPRs (MFMA A/B frag)
typedef __attribute__((ext_vector_type(4))) float f32x4;    // MFMA C/D frag

// LDS row pad: 128 + 8 bf16 -> row stride 272 B (16B-aligned, 2-way bank aliasing = free)
#define WLD  136

// ---------------------------------------------------------------------------
// Kernel 1: W [8][128][128] fp32  ->  Wt [8][q][d] bf16 (transposed, RNE)
// Reads coalesced along q; scattered 2B writes land in L2 (512 KB footprint).
// ---------------------------------------------------------------------------
__global__ void wt_transpose_kernel(const float* __restrict__ W,
                                    __hip_bfloat16* __restrict__ Wt) {
    int idx = blockIdx.x * 256 + threadIdx.x;      // ordered (s, d, q): coalesced read
    int q = idx & 127;
    int d = (idx >> 7) & 127;
    int s = idx >> 14;
    float v = W[idx];                              // W[s][d][q]
    Wt[s * (DIN * DOUT) + q * DIN + d] = __float2bfloat16(v);
}

// ---------------------------------------------------------------------------
// Kernel 2: per-sample GEMM  out[n] = x[n] (64x128) @ W[s(n)] (128x128)
// 1 block / sample, 4 waves; wave w computes rows [16w, 16w+16).
// ---------------------------------------------------------------------------
__global__ __launch_bounds__(256, 4)
void combine_kernel(const float* __restrict__ x,
                    const int* __restrict__ sp,
                    const __hip_bfloat16* __restrict__ Wt,
                    float* __restrict__ out) {
    __shared__ ushort wlds[DOUT * WLD];            // 128 rows (q) x 136 bf16 = 34816 B

    const int n   = blockIdx.x;
    const int tid = threadIdx.x;
    const int s   = sp[n];                         // uniform -> scalar load

    // ---- stage Wt[s] (128x128 bf16 = 2048 x 16B) into padded LDS ----
    {
        const uint4* src = reinterpret_cast<const uint4*>(Wt + (size_t)s * (DIN * DOUT));
        #pragma unroll
        for (int i = 0; i < 8; ++i) {
            int f = tid + i * 256;                 // uint4 index in [0, 2048)
            uint4 v = src[f];
            int q  = f >> 4;                       // row (8 bf16 per uint4, 16 uint4/row)
            int db = (f & 15) << 3;                // d offset in bf16
            *reinterpret_cast<uint4*>(&wlds[q * WLD + db]) = v;
        }
    }
    __syncthreads();

    const int lane = tid & 63;
    const int wave = tid >> 6;
    const int col  = lane & 15;                    // A row / B col / D col
    const int quad = lane >> 4;

    // ---- A fragments straight from global (no reuse across waves) ----
    // A[m = 16*wave + col][k = quad*8 + j + 32*kstep], j contiguous -> 2x float4
    const float* xrow = x + (size_t)n * (NC * DIN) + (wave * 16 + col) * DIN + quad * 8;
    short8 a[4];
    #pragma unroll
    for (int k = 0; k < 4; ++k) {
        const float4* p = reinterpret_cast<const float4*>(xrow + k * 32);
        float4 p0 = p[0];
        float4 p1 = p[1];
        union { short8 v; short2 h[4]; } u;
        union { __hip_bfloat162 b; short2 s2; } c;
        c.b = __float22bfloat162_rn(make_float2(p0.x, p0.y)); u.h[0] = c.s2;
        c.b = __float22bfloat162_rn(make_float2(p0.z, p0.w)); u.h[1] = c.s2;
        c.b = __float22bfloat162_rn(make_float2(p1.x, p1.y)); u.h[2] = c.s2;
        c.b = __float22bfloat162_rn(make_float2(p1.z, p1.w)); u.h[3] = c.s2;
        a[k] = u.v;
    }

    // ---- MFMA: 8 N-tiles x 4 K-steps ----
    f32x4 acc[8];
    #pragma unroll
    for (int t = 0; t < 8; ++t) acc[t] = (f32x4){0.f, 0.f, 0.f, 0.f};

    #pragma unroll
    for (int nt = 0; nt < 8; ++nt) {
        // B[k = quad*8 + j + 32*kstep][n = nt*16 + col] = Wt_lds[nt*16+col][k]
        const ushort* brow = &wlds[(nt * 16 + col) * WLD + quad * 8];
        #pragma unroll
        for (int k = 0; k < 4; ++k) {
            short8 b = *reinterpret_cast<const short8*>(brow + k * 32);
            acc[nt] = __builtin_amdgcn_mfma_f32_16x16x32_bf16(a[k], b, acc[nt], 0, 0, 0);
        }
    }

    // ---- store: D[row = quad*4 + r][col], 16-lane contiguous 64B segments ----
    float* op = out + (size_t)n * (NC * DOUT) + (wave * 16) * DOUT;
    #pragma unroll
    for (int nt = 0; nt < 8; ++nt) {
        union { f32x4 v; float f[4]; } u;
        u.v = acc[nt];
        #pragma unroll
        for (int r = 0; r < 4; ++r) {
            op[(quad * 4 + r) * DOUT + nt * 16 + col] = u.f[r];
        }
    }
}

// ---------------------------------------------------------------------------
extern "C" void kernel_launch(void* const* d_in, const int* in_sizes, int n_in,
                              void* d_out, int out_size, void* d_ws, size_t ws_size,
                              hipStream_t stream) {
    const float* x  = (const float*)d_in[0];   // [16384, 64, 128] fp32
    const int*   sp = (const int*)d_in[1];     // [16384] int
    const float* W  = (const float*)d_in[2];   // [8, 128, 128] fp32
    float* out = (float*)d_out;                // [16384, 64, 128] fp32
    __hip_bfloat16* Wt = (__hip_bfloat16*)d_ws;  // 8*128*128*2 = 256 KB scratch

    wt_transpose_kernel<<<(NSP * DIN * DOUT) / 256, 256, 0, stream>>>(W, Wt);
    combine_kernel<<<NS, 256, 0, stream>>>(x, sp, Wt, out);
}